// Round 1
// 1218.051 us; speedup vs baseline: 1.1018x; 1.1018x over previous
//
#include <hip/hip_runtime.h>
#include <hip/hip_bf16.h>
#include <stdint.h>
#include <string.h>

#define HIDDEN 1024
#define FEAT   512
#define PREV   10
#define PRED   20
#define BATCH  1024
#define KTOT   (HIDDEN + FEAT)   // 1536
#define N4H    4096
#define TSTEPS (PREV + PRED)     // 30
#define NBLK   256               // 1 block/CU on 256 CUs
#define NTHR   512
#define NKT    24                // KTOT/64 k-tiles
#define BUFB   49152             // per-stage buffer: A 16K + B 32K

typedef __attribute__((ext_vector_type(8))) short short8;
typedef __attribute__((ext_vector_type(4))) float f32x4;
typedef unsigned long long ull;

// ---- async global->LDS 16B copy (wave-uniform LDS base + lane*16), plain-cached ----
typedef __attribute__((address_space(3))) unsigned int u32_lds;
typedef const __attribute__((address_space(1))) unsigned int u32_gbl;

__device__ __forceinline__ void async16(void* lds, const void* g) {
  u32_lds* lp = (u32_lds*)(unsigned int)(uintptr_t)lds;
  u32_gbl* gp = (u32_gbl*)(uintptr_t)g;
  __builtin_amdgcn_global_load_lds(gp, lp, 16, 0, 0);
}

__device__ __forceinline__ float sigmoidf_(float x) {
  return 1.0f / (1.0f + __expf(-x));
}
__device__ __forceinline__ float tanhf_(float x) {
  return 1.0f - 2.0f / (1.0f + __expf(2.0f * x));
}

// device-coherent (LLC) 8B load/store — bypass the non-coherent L1/L2
__device__ __forceinline__ ull cload(const void* p) {
  return __hip_atomic_load((const ull*)p, __ATOMIC_RELAXED, __HIP_MEMORY_SCOPE_AGENT);
}
__device__ __forceinline__ void cstore(void* p, ull v) {
  __hip_atomic_store((ull*)p, v, __ATOMIC_RELAXED, __HIP_MEMORY_SCOPE_AGENT);
}

// device-coherent 16B load, NO wait (counted by our manual vmcnt discipline).
// sc1 == agent-scope relaxed load (same coherence point/LLC as cload above).
__device__ __forceinline__ f32x4 cload16a(const void* p) {
  f32x4 r;
  asm volatile("global_load_dwordx4 %0, %1, off sc1"
               : "=v"(r) : "v"(p) : "memory");
  return r;
}

// ---- pack [Wh;Wx] (fp32, [K,4096] gate-blocked) -> WpT (bf16, [4096,K], gate-interleaved n=4j+g) ----
__global__ void pack_w_kernel(const float* __restrict__ Wx, const float* __restrict__ Wh,
                              __hip_bfloat16* __restrict__ WpT) {
  __shared__ float tile[64][65];
  const int k0 = blockIdx.x * 64, n0 = blockIdx.y * 64;
  const int tid = threadIdx.x;
  const float* src = (k0 < HIDDEN) ? (Wh + (size_t)k0 * N4H) : (Wx + (size_t)(k0 - HIDDEN) * N4H);
  {
    const int jl = tid & 15, g = (tid >> 4) & 3, klb = tid >> 6;
#pragma unroll
    for (int it = 0; it < 16; ++it) {
      int kl = klb + it * 4;
      tile[kl][4 * jl + g] = src[(size_t)kl * N4H + g * HIDDEN + (n0 >> 2) + jl];
    }
  }
  __syncthreads();
  {
    const int kl = tid & 63, nlb = tid >> 6;
#pragma unroll
    for (int it = 0; it < 16; ++it) {
      int nl = nlb + it * 4;
      WpT[(size_t)(n0 + nl) * KTOT + k0 + kl] = __float2bfloat16(tile[kl][nl]);
    }
  }
}

__global__ void pack_bias_kernel(const float* __restrict__ b, float* __restrict__ bp) {
  int n = blockIdx.x * 256 + threadIdx.x;
  if (n < N4H) bp[n] = b[(n & 3) * HIDDEN + (n >> 2)];
}

// ---- convert inputs fp32 -> bf16 ----
__global__ void cvt_x_kernel(const float* __restrict__ xr, const float* __restrict__ xf,
                             __hip_bfloat16* __restrict__ xrb, __hip_bfloat16* __restrict__ xfb) {
  const int NR4 = BATCH * TSTEPS * FEAT / 4;
  const int NF4 = BATCH * PRED * FEAT / 4;
  int i = blockIdx.x * 256 + threadIdx.x;
  float4 v;
  __hip_bfloat16* dst;
  if (i < NR4) {
    v = ((const float4*)xr)[i];
    dst = xrb + (size_t)i * 4;
  } else {
    int j = i - NR4;
    if (j >= NF4) return;
    v = ((const float4*)xf)[j];
    dst = xfb + (size_t)j * 4;
  }
  dst[0] = __float2bfloat16(v.x);
  dst[1] = __float2bfloat16(v.y);
  dst[2] = __float2bfloat16(v.z);
  dst[3] = __float2bfloat16(v.w);
}

// ---- persistent LSTM ----
// 256 blocks x 512 thr, 1 block/CU. Block tile 128 rows x 256 n-cols;
// 8 waves as 2x4 grid of 64x64 wave tiles (4x4 MFMA fragments each).
// k-loop: 24 x 64-k tiles, TRIPLE-buffered LDS (3 x 48KB), stage(kt+2)
// issued while computing kt; raw s_barrier + counted s_waitcnt vmcnt(12)
// so staging loads stay in flight across barriers (never drain to 0
// mid-loop). Weights/x staged via global_load_lds (6 vm-ops per stage,
// uniform); h staged via 16B sc1 loads into regs 2 tiles ahead, ds_write'd
// just before the consuming barrier. h traffic stays LLC-coherent (sc1),
// cell state in registers (16/thread).
__global__ __launch_bounds__(512, 2)
void lstm_persistent(const __hip_bfloat16* __restrict__ xrb,
                     const __hip_bfloat16* __restrict__ xfb,
                     const __hip_bfloat16* __restrict__ WpT,
                     const float* __restrict__ biasp,
                     const float* __restrict__ w2,
                     __hip_bfloat16* __restrict__ hb0,
                     __hip_bfloat16* __restrict__ hb1,
                     float* __restrict__ cbuf,
                     float* __restrict__ accout,
                     unsigned* __restrict__ bar) {
  __shared__ __align__(16) char smem[3 * BUFB];  // 144 KB; z-epilogue (128x132 f32) overlays

  const int tid = threadIdx.x;
  const int bid = blockIdx.x;
  const int nt = bid & 15, rt = bid >> 4;       // bid%8 == nt%8 -> per-XCD weight slice is 2x786KB, L2-resident
  const int n0 = nt * 256;
  const int r0 = rt * 128;
  const int w = tid >> 6, l = tid & 63;
  const int sub = l >> 3;
  const int csrc = (l & 7) ^ sub;               // XOR-swizzled 16B source chunk
  const int quad = l >> 4, lrow = l & 15;
  const int wm = w >> 2, wn = w & 3;            // wave tile: rows wm*64+64, cols wn*64+64
  const int row_e = tid >> 2, jq = tid & 3;     // epilogue: 128 rows x 4 j-octets
  unsigned* cnt = bar;
  unsigned* flag = bar + 32;

  const unsigned short* wp_us = (const unsigned short*)WpT;
  // B staging source base (step-invariant): rows n0 + w*32 + it*8 + sub
  const unsigned short* bS = wp_us + (size_t)(n0 + w * 32 + sub) * KTOT + csrc * 8;
  const int ldsAwr = (w * 16 + sub) * 128 + (l & 7) * 16;  // manual A deposit (matches async16 layout)

  float creg[16];
#pragma unroll
  for (int i = 0; i < 16; ++i) creg[i] = 0.f;

// ---- stage k-tile S into buffer at byte-offset OFF; h-range loads go to regs SA/SB ----
#define ISSUE_STAGE(S, OFF, SA, SB)                                                   \
  do {                                                                                \
    const int _s = (S);                                                               \
    char* _sb = smem + (OFF);                                                         \
    async16(_sb + 16384 + (w * 32 + 0) * 128,  bS + (size_t)0 * 8 * KTOT + _s * 64);  \
    async16(_sb + 16384 + (w * 32 + 8) * 128,  bS + (size_t)1 * 8 * KTOT + _s * 64);  \
    async16(_sb + 16384 + (w * 32 + 16) * 128, bS + (size_t)2 * 8 * KTOT + _s * 64);  \
    async16(_sb + 16384 + (w * 32 + 24) * 128, bS + (size_t)3 * 8 * KTOT + _s * 64);  \
    if (_s < 16) {                                                                    \
      SA = cload16a(hsA0 + (size_t)_s * 64);                                          \
      SB = cload16a(hsA1 + (size_t)_s * 64);                                          \
    } else {                                                                          \
      async16(_sb + (w * 16) * 128,     xA0 + (size_t)(_s * 64 - HIDDEN));            \
      async16(_sb + (w * 16 + 8) * 128, xA1 + (size_t)(_s * 64 - HIDDEN));            \
    }                                                                                 \
  } while (0)

#define WRITE_A(OFFC, CA, CB)                                                         \
  do {                                                                                \
    *(f32x4*)(smem + (OFFC) + ldsAwr) = CA;                                           \
    *(f32x4*)(smem + (OFFC) + ldsAwr + 1024) = CB;                                    \
  } while (0)

#define KT_COMPUTE(OFFC)                                                              \
  do {                                                                                \
    const char* _ca = smem + (OFFC);                                                  \
    const char* _cb = _ca + 16384;                                                    \
    _Pragma("unroll")                                                                 \
    for (int kk = 0; kk < 2; ++kk) {                                                  \
      const int swz = (((kk << 2) + quad) ^ (lrow & 7)) * 16;                         \
      short8 af[4], bf[4];                                                            \
      _Pragma("unroll")                                                               \
      for (int mi = 0; mi < 4; ++mi)                                                  \
        af[mi] = *(const short8*)(_ca + (wm * 64 + mi * 16 + lrow) * 128 + swz);      \
      _Pragma("unroll")                                                               \
      for (int ni = 0; ni < 4; ++ni)                                                  \
        bf[ni] = *(const short8*)(_cb + (wn * 64 + ni * 16 + lrow) * 128 + swz);      \
      _Pragma("unroll")                                                               \
      for (int mi = 0; mi < 4; ++mi)                                                  \
        _Pragma("unroll")                                                             \
        for (int ni = 0; ni < 4; ++ni)                                                \
          acc[mi][ni] = __builtin_amdgcn_mfma_f32_16x16x32_bf16(af[mi], bf[ni],       \
                                                                acc[mi][ni], 0, 0, 0);\
    }                                                                                 \
  } while (0)

// One 64-k tile: issue stage(kt+2), counted vmcnt wait for stage(kt),
// deposit h regs (h-range), raw barrier, MFMA, raw barrier.
#define KT_BODY(KT, OFFC, OFFS, CA, CB, SA, SB)                                       \
  do {                                                                                \
    if ((KT) < NKT - 2) ISSUE_STAGE((KT) + 2, OFFS, SA, SB);                          \
    if ((KT) < NKT - 2) {                                                             \
      asm volatile("s_waitcnt vmcnt(12)" ::: "memory");                               \
    } else if ((KT) == NKT - 2) {                                                     \
      asm volatile("s_waitcnt vmcnt(6)" ::: "memory");                                \
    } else {                                                                          \
      asm volatile("s_waitcnt vmcnt(0)" ::: "memory");                                \
    }                                                                                 \
    __builtin_amdgcn_sched_barrier(0);                                                \
    if ((KT) < 16) {                                                                  \
      WRITE_A(OFFC, CA, CB);                                                          \
      asm volatile("s_waitcnt lgkmcnt(0)" ::: "memory");                              \
      __builtin_amdgcn_sched_barrier(0);                                              \
    }                                                                                 \
    __builtin_amdgcn_s_barrier();                                                     \
    __builtin_amdgcn_sched_barrier(0);                                                \
    KT_COMPUTE(OFFC);                                                                 \
    asm volatile("" ::: "memory");                                                    \
    __builtin_amdgcn_s_barrier();                                                     \
  } while (0)

#pragma unroll 1
  for (int t = 0; t < TSTEPS; ++t) {
    const unsigned short* hcur = (const unsigned short*)((t & 1) ? hb1 : hb0);
    unsigned short* hnx = (unsigned short*)((t & 1) ? hb0 : hb1);
    const bool active = (t >= PREV) || (rt < 8);

    if (active) {
      if (t == PREV && r0 >= BATCH) {
        // fork: pick up cell state written at t==9 by real-row owners (LLC-coherent).
        // Done (and compiler-waited) BEFORE any staging issue so vmcnt counting stays exact.
#pragma unroll
        for (int h2 = 0; h2 < 2; ++h2)
#pragma unroll
          for (int q = 0; q < 4; ++q) {
            size_t base = (size_t)(r0 - BATCH + row_e) * HIDDEN + nt * 64 + h2 * 32 + jq * 8 + q * 2;
            ull d = cload(&cbuf[base]);
            float2 f = *(float2*)&d;
            creg[h2 * 8 + q * 2 + 0] = f.x;
            creg[h2 * 8 + q * 2 + 1] = f.y;
          }
      }
      const int r0h = (t == PREV && r0 >= BATCH) ? (r0 - BATCH) : r0;

      const unsigned short* hsA0 = hcur + (size_t)(r0h + w * 16 + sub) * HIDDEN + csrc * 8;
      const unsigned short* hsA1 = hsA0 + 8 * HIDDEN;
      const unsigned short* xb;
      size_t xstr;
      if (r0 < BATCH) {
        xb = (const unsigned short*)xrb + ((size_t)r0 * TSTEPS + t) * FEAT;
        xstr = (size_t)TSTEPS * FEAT;
      } else {
        xb = (const unsigned short*)xfb + ((size_t)(r0 - BATCH) * PRED + (t - PREV)) * FEAT;
        xstr = (size_t)PRED * FEAT;
      }
      const unsigned short* xA0 = xb + (w * 16 + sub) * xstr + csrc * 8;
      const unsigned short* xA1 = xA0 + 8 * xstr;

      f32x4 acc[4][4];
#pragma unroll
      for (int a = 0; a < 4; ++a)
#pragma unroll
        for (int b_ = 0; b_ < 4; ++b_) acc[a][b_] = (f32x4){0.f, 0.f, 0.f, 0.f};

      f32x4 h0a, h0b, h1a, h1b, h2a, h2b;
      ISSUE_STAGE(0, 0, h0a, h0b);
      ISSUE_STAGE(1, BUFB, h1a, h1b);

#pragma unroll 1
      for (int m = 0; m < 8; ++m) {
        const int kt = 3 * m;
        KT_BODY(kt + 0, 0,        2 * BUFB, h0a, h0b, h2a, h2b);
        KT_BODY(kt + 1, BUFB,     0,        h1a, h1b, h0a, h0b);
        KT_BODY(kt + 2, 2 * BUFB, BUFB,     h2a, h2b, h1a, h1b);
      }

      // ---- epilogue: two 128-col passes; z 128x132 f32 overlays staging LDS ----
      float* zb = (float*)smem;
      const int kout = t - PREV;
#pragma unroll
      for (int h2 = 0; h2 < 2; ++h2) {
        if ((wn >> 1) == h2) {
          const int cb = (wn & 1) * 64;
#pragma unroll
          for (int mi = 0; mi < 4; ++mi)
#pragma unroll
            for (int ni = 0; ni < 4; ++ni) {
              f32x4 v = acc[mi][ni];
              int col = cb + ni * 16 + lrow;
              int rb = wm * 64 + mi * 16 + quad * 4;
#pragma unroll
              for (int r = 0; r < 4; ++r) zb[(rb + r) * 132 + col] = v[r];
            }
        }
        __syncthreads();
        // gates: 128 rows x 32 j per pass; thread -> (row_e, j = jq*8+it)
        const int jg0 = nt * 64 + h2 * 32 + jq * 8;
        const float4 w2a = *(const float4*)&w2[jg0];
        const float4 w2b = *(const float4*)&w2[jg0 + 4];
        float w2r[8] = {w2a.x, w2a.y, w2a.z, w2a.w, w2b.x, w2b.y, w2b.z, w2b.w};
        unsigned short hsv[8];
        float cnv[8];
        float psum = 0.f;
#pragma unroll
        for (int it = 0; it < 8; ++it) {
          int jloc = jq * 8 + it;
          float4 z4 = *(float4*)&zb[row_e * 132 + jloc * 4];
          float4 bi = *(const float4*)&biasp[n0 + h2 * 128 + jloc * 4];
          float gi = sigmoidf_(z4.x + bi.x);
          float gf = sigmoidf_(z4.y + bi.y);
          float gg = tanhf_(z4.z + bi.z);
          float go = sigmoidf_(z4.w + bi.w);
          int ci = h2 * 8 + it;
          float cnew = gf * creg[ci] + gi * gg;
          float hnew = go * tanhf_(cnew);
          creg[ci] = cnew;
          cnv[it] = cnew;
          __hip_bfloat16 hbv = __float2bfloat16(hnew);
          hsv[it] = *(unsigned short*)&hbv;
          if (t >= PREV) psum += hnew * w2r[it];
        }
        const int rg = r0 + row_e;
        {
          ull p0, p1;
          memcpy(&p0, &hsv[0], 8);
          memcpy(&p1, &hsv[4], 8);
          cstore(hnx + (size_t)rg * HIDDEN + jg0, p0);      // device-coherent h write
          cstore(hnx + (size_t)rg * HIDDEN + jg0 + 4, p1);
        }
        if (t == PREV - 1) {
#pragma unroll
          for (int q = 0; q < 4; ++q) {
            ull d;
            memcpy(&d, &cnv[2 * q], 8);
            cstore(&cbuf[(size_t)rg * HIDDEN + jg0 + 2 * q], d);
          }
        }
        if (t >= PREV) {
          psum += __shfl_down(psum, 2, 4);
          psum += __shfl_down(psum, 1, 4);
          if (jq == 0) atomicAdd(&accout[rg * PRED + kout], psum);
        }
        __syncthreads();
      }
    }

    // ---- grid barrier (LLC atomics); raw s_barrier + explicit store drain ----
    if (t < TSTEPS - 1) {
      asm volatile("s_waitcnt vmcnt(0)" ::: "memory");  // h/c stores at LLC before signal
      __builtin_amdgcn_s_barrier();
      if (tid == 0) {
        unsigned ph = (unsigned)(t + 1);
        unsigned old = __hip_atomic_fetch_add(cnt, 1u, __ATOMIC_RELAXED, __HIP_MEMORY_SCOPE_AGENT);
        if (old == NBLK - 1) {
          __hip_atomic_store(cnt, 0u, __ATOMIC_RELAXED, __HIP_MEMORY_SCOPE_AGENT);
          __hip_atomic_store(flag, ph, __ATOMIC_RELAXED, __HIP_MEMORY_SCOPE_AGENT);
        } else {
          while (__hip_atomic_load(flag, __ATOMIC_RELAXED, __HIP_MEMORY_SCOPE_AGENT) < ph)
            __builtin_amdgcn_s_sleep(4);
        }
      }
      __builtin_amdgcn_s_barrier();
    }
  }
#undef ISSUE_STAGE
#undef WRITE_A
#undef KT_COMPUTE
#undef KT_BODY
}

// ---- final tanh chain over the 40960 fused dots ----
__global__ void final_kernel(const float* __restrict__ accout, const float* __restrict__ b2,
                             const float* __restrict__ w3, const float* __restrict__ b3,
                             const float* __restrict__ w4, const float* __restrict__ b4,
                             float* __restrict__ out) {
  int i = blockIdx.x * 256 + threadIdx.x;
  const int half = BATCH * PRED;
  if (i >= 2 * half) return;
  int r, k;
  if (i < half) {
    r = i / PRED;
    k = i % PRED;
  } else {
    r = BATCH + (i - half) / PRED;
    k = (i - half) % PRED;
  }
  float x = tanhf_(accout[r * PRED + k] + b2[0]);
  x = tanhf_(x * w3[0] + b3[0]);
  x = tanhf_(x * w4[0] + b4[0]);
  out[i] = x;
}

extern "C" void kernel_launch(void* const* d_in, const int* in_sizes, int n_in,
                              void* d_out, int out_size, void* d_ws, size_t ws_size,
                              hipStream_t stream) {
  const float* real_input = (const float*)d_in[0];
  const float* fake_input = (const float*)d_in[1];
  const float* Wx = (const float*)d_in[2];
  const float* Wh = (const float*)d_in[3];
  const float* b  = (const float*)d_in[4];
  const float* w2 = (const float*)d_in[5];
  const float* b2 = (const float*)d_in[6];
  const float* w3 = (const float*)d_in[7];
  const float* b3 = (const float*)d_in[8];
  const float* w4 = (const float*)d_in[9];
  const float* b4 = (const float*)d_in[10];
  float* out = (float*)d_out;

  char* ws = (char*)d_ws;
  size_t off = 0;
  __hip_bfloat16* WpT = (__hip_bfloat16*)(ws + off);  off += (size_t)N4H * KTOT * 2;
  float* biasp = (float*)(ws + off);                  off += (size_t)N4H * 4;
  __hip_bfloat16* xrb = (__hip_bfloat16*)(ws + off);  off += (size_t)BATCH * TSTEPS * FEAT * 2;
  __hip_bfloat16* xfb = (__hip_bfloat16*)(ws + off);  off += (size_t)BATCH * PRED * FEAT * 2;
  __hip_bfloat16* hb0 = (__hip_bfloat16*)(ws + off);  off += (size_t)2 * BATCH * HIDDEN * 2;
  __hip_bfloat16* hb1 = (__hip_bfloat16*)(ws + off);  off += (size_t)2 * BATCH * HIDDEN * 2;
  float* cbuf = (float*)(ws + off);                   off += (size_t)BATCH * HIDDEN * 4;
  float* accout = (float*)(ws + off);                 off += (size_t)2 * BATCH * PRED * 4;
  unsigned* bar = (unsigned*)(ws + off);              off += 256;

  hipMemsetAsync(hb0, 0, (size_t)2 * BATCH * HIDDEN * 2, stream);
  hipMemsetAsync(accout, 0, (size_t)2 * BATCH * PRED * 4, stream);
  hipMemsetAsync(bar, 0, 256, stream);

  pack_w_kernel<<<dim3(KTOT / 64, N4H / 64), 256, 0, stream>>>(Wx, Wh, WpT);
  pack_bias_kernel<<<N4H / 256, 256, 0, stream>>>(b, biasp);
  {
    int n4 = BATCH * TSTEPS * FEAT / 4 + BATCH * PRED * FEAT / 4;
    cvt_x_kernel<<<(n4 + 255) / 256, 256, 0, stream>>>(real_input, fake_input, xrb, xfb);
  }

  {
    const __hip_bfloat16* a_xrb = xrb;
    const __hip_bfloat16* a_xfb = xfb;
    const __hip_bfloat16* a_WpT = WpT;
    const float* a_biasp = biasp;
    const float* a_w2 = w2;
    __hip_bfloat16* a_hb0 = hb0;
    __hip_bfloat16* a_hb1 = hb1;
    float* a_cbuf = cbuf;
    float* a_acc = accout;
    unsigned* a_bar = bar;
    void* args[10] = {&a_xrb, &a_xfb, &a_WpT, &a_biasp, &a_w2,
                      &a_hb0, &a_hb1, &a_cbuf, &a_acc, &a_bar};
    hipError_t e = hipLaunchCooperativeKernel((const void*)lstm_persistent,
                                              dim3(NBLK), dim3(NTHR), args, 0, stream);
    if (e != hipSuccess) {
      // co-residency fallback: 256 blocks at 144 KB LDS are 1/CU resident
      lstm_persistent<<<dim3(NBLK), dim3(NTHR), 0, stream>>>(
          xrb, xfb, WpT, biasp, w2, hb0, hb1, cbuf, accout, bar);
    }
  }

  final_kernel<<<(2 * BATCH * PRED + 255) / 256, 256, 0, stream>>>(accout, b2, w3, b3, w4, b4, out);
}